// Round 3
// baseline (345.004 us; speedup 1.0000x reference)
//
#include <hip/hip_runtime.h>

// Maj3: out[b,o,h,w] = sum_{kh,c} sign( sum_{kw} x[b,c,h+kh-1,w+kw-1] * W[o,kw,kh,c] )
// x: (4,64,56,56) f32; W: (64,3,3,64) f32; out: (4,64,56,56) f32.
// Bit-exactness vs numpy required (integer output, threshold 1.36): no FMA
// contraction, same mul/add order, sign(0)=0 only from fully-pad rows (skipped).
//
// R3: R2 was per-wave-serialized by `asm volatile` (scheduling-region barrier
// x3000/wave -> VALUBusy 16%). Non-volatile empty asm still blocks FMA
// contraction (product is opaque) but is freely schedulable; pragma is
// belt-and-suspenders. Config unchanged from R2 to isolate the effect.

#define Bn 4
#define Cn 64
#define Hn 56
#define Wn 56
#define On 64
#define OG 4    // output channels per block (uniform -> scalar weight loads)
#define CH 32   // channels per wave (c-half)

// Plain IEEE fp32 mul that cannot be contracted into v_fmac by the consumer
// add (value tied through an opaque no-op asm), but NOT volatile -> the
// scheduler may still hoist loads / pipeline across it.
__device__ __forceinline__ float mulrn(float a, float b) {
    float p = a * b;
    asm("" : "+v"(p));
    return p;
}

__global__ __launch_bounds__(512, 7)
void maj3_kernel(const float* __restrict__ x,
                 const float* __restrict__ wt,
                 float* __restrict__ out)
{
#pragma clang fp contract(off)
    __shared__ int lds[4][OG][64];

    const int lane  = threadIdx.x & 63;
    const int wave  = threadIdx.x >> 6;   // 0..7
    const int r     = wave & 3;           // row slot within block
    const int chalf = wave >> 2;          // 0 / 1: which 32-channel half
    const int bh    = blockIdx.x * 4 + r; // 0..223
    const int b     = bh / Hn;
    const int h     = bh - b * Hn;
    const int og    = blockIdx.y * OG;    // block-uniform o base

    const int wc    = lane;               // pixel column; lanes >=56 inactive
    const bool act  = wc < Wn;

    // Clamped tap addresses (never OOB) + per-tap validity for zero padding.
    const int c0 = min(max(wc - 1, 0), Wn - 1);
    const int c1 = min(wc, Wn - 1);
    const int c2 = min(wc + 1, Wn - 1);
    const bool f0 = (wc >= 1);
    const bool f1 = act;
    const bool f2 = (wc + 1 < Wn);

    int acc[OG];
    #pragma unroll
    for (int i = 0; i < OG; ++i) acc[i] = 0;

    int nvalid = 0;
    const float* xb = x + b * (Cn * Hn * Wn) + chalf * (CH * Hn * Wn);

    for (int kh = 0; kh < 3; ++kh) {
        const int row = h + kh - 1;
        if (row < 0 || row >= Hn) continue;   // fully-pad row: sign(0)=0, skip
        ++nvalid;
        const float* xr = xb + row * Wn;
        #pragma unroll 8
        for (int c = 0; c < CH; ++c) {
            const float* xc = xr + c * (Hn * Wn);
            const float v0 = xc[c0];
            const float v1 = xc[c1];
            const float v2 = xc[c2];
            const float x0 = f0 ? v0 : 0.0f;
            const float x1 = f1 ? v1 : 0.0f;
            const float x2 = f2 ? v2 : 0.0f;
            #pragma unroll
            for (int oo = 0; oo < OG; ++oo) {
                // W[o,kw,kh,c] = wt[o*576 + kw*192 + kh*64 + c]; wave-uniform
                // address -> s_load path; c-contiguous -> s_load_dwordx8 clusters.
                const float* wp = wt + (og + oo) * (3 * 3 * Cn) + kh * Cn
                                + chalf * CH + c;
                const float p0 = mulrn(x0, wp[0 * 3 * Cn]);
                const float p1 = mulrn(x1, wp[1 * 3 * Cn]);
                const float p2 = mulrn(x2, wp[2 * 3 * Cn]);
                const float s  = (p0 + p1) + p2;   // same order as reference
                acc[oo] += (int)(__float_as_uint(s) >> 31);  // count negatives
            }
        }
    }

    // Combine the two c-halves' negative-counts (integer -> exact).
    if (chalf == 1) {
        #pragma unroll
        for (int oo = 0; oo < OG; ++oo) lds[r][oo][lane] = acc[oo];
    }
    __syncthreads();
    if (chalf == 0 && act) {
        float* ob = out + ((b * On + og) * Hn + h) * Wn + wc;
        const float base = (float)(nvalid * Cn);
        #pragma unroll
        for (int oo = 0; oo < OG; ++oo) {
            const int total = acc[oo] + lds[r][oo][lane];
            ob[oo * Hn * Wn] = base - 2.0f * (float)total;  // N - 2*negcount
        }
    }
}

extern "C" void kernel_launch(void* const* d_in, const int* in_sizes, int n_in,
                              void* d_out, int out_size, void* d_ws, size_t ws_size,
                              hipStream_t stream) {
    const float* x  = (const float*)d_in[0];
    const float* wt = (const float*)d_in[1];
    float* o        = (float*)d_out;
    dim3 grid(56, 16);   // 56 row-blocks (4 rows each) x 16 o-groups of 4
    maj3_kernel<<<grid, dim3(512), 0, stream>>>(x, wt, o);
}

// Round 4
// 92.348 us; speedup vs baseline: 3.7359x; 3.7359x over previous
//
#include <hip/hip_runtime.h>

// Maj3: out[b,o,h,w] = sum_{kh,c} sign( sum_{kw} x[b,c,h+kh-1,w+kw-1] * W[o,kw,kh,c] )
// x: (4,64,56,56) f32; W: (64,3,3,64) f32; out: (4,64,56,56) f32.
// Bit-exactness vs numpy required (integer output, threshold 1.36): no FMA
// contraction (pragma), same mul/add order, sign(0)=0 only from fully-pad rows.
//
// R4: R3's non-volatile asm caused live-range explosion -> ~1.2 GB/dispatch of
// scratch spill (FETCH 376MB/WRITE 810MB). Fix: drop asm entirely, rely on
// `#pragma clang fp contract(off)` (hipcc default fast-honor-pragmas honors it);
// unroll 8->4; launch_bounds(512,4) -> 128-VGPR cap, no spills, 16 waves/CU.

#define Bn 4
#define Cn 64
#define Hn 56
#define Wn 56
#define On 64
#define OG 4    // output channels per block (uniform -> scalar weight loads)
#define CH 32   // channels per wave (c-half)

__global__ __launch_bounds__(512, 4)
void maj3_kernel(const float* __restrict__ x,
                 const float* __restrict__ wt,
                 float* __restrict__ out)
{
#pragma clang fp contract(off)
    __shared__ int lds[4][OG][64];

    const int lane  = threadIdx.x & 63;
    const int wave  = threadIdx.x >> 6;   // 0..7
    const int r     = wave & 3;           // row slot within block
    const int chalf = wave >> 2;          // 0 / 1: which 32-channel half
    const int bh    = blockIdx.x * 4 + r; // 0..223
    const int b     = bh / Hn;
    const int h     = bh - b * Hn;
    const int og    = blockIdx.y * OG;    // block-uniform o base

    const int wc    = lane;               // pixel column; lanes >=56 inactive
    const bool act  = wc < Wn;

    // Clamped tap addresses (never OOB) + per-tap validity for zero padding.
    const int c0 = min(max(wc - 1, 0), Wn - 1);
    const int c1 = min(wc, Wn - 1);
    const int c2 = min(wc + 1, Wn - 1);
    const bool f0 = (wc >= 1);
    const bool f1 = act;
    const bool f2 = (wc + 1 < Wn);

    int acc[OG];
    #pragma unroll
    for (int i = 0; i < OG; ++i) acc[i] = 0;

    int nvalid = 0;
    const float* xb = x + b * (Cn * Hn * Wn) + chalf * (CH * Hn * Wn);

    for (int kh = 0; kh < 3; ++kh) {
        const int row = h + kh - 1;
        if (row < 0 || row >= Hn) continue;   // fully-pad row: sign(0)=0, skip
        ++nvalid;
        const float* xr = xb + row * Wn;
        #pragma unroll 4
        for (int c = 0; c < CH; ++c) {
            const float* xc = xr + c * (Hn * Wn);
            const float v0 = xc[c0];
            const float v1 = xc[c1];
            const float v2 = xc[c2];
            const float x0 = f0 ? v0 : 0.0f;
            const float x1 = f1 ? v1 : 0.0f;
            const float x2 = f2 ? v2 : 0.0f;
            #pragma unroll
            for (int oo = 0; oo < OG; ++oo) {
                // W[o,kw,kh,c] = wt[o*576 + kw*192 + kh*64 + c]; wave-uniform
                // address, c-contiguous -> s_load_dwordx4 clusters across unroll.
                const float* wp = wt + (og + oo) * (3 * 3 * Cn) + kh * Cn
                                + chalf * CH + c;
                const float p0 = x0 * wp[0 * 3 * Cn];   // contract(off):
                const float p1 = x1 * wp[1 * 3 * Cn];   //   plain v_mul_f32,
                const float p2 = x2 * wp[2 * 3 * Cn];   //   no v_fmac fusion
                const float s  = (p0 + p1) + p2;        // same order as reference
                acc[oo] += (int)(__float_as_uint(s) >> 31);  // count negatives
            }
        }
    }

    // Combine the two c-halves' negative-counts (integer -> exact).
    if (chalf == 1) {
        #pragma unroll
        for (int oo = 0; oo < OG; ++oo) lds[r][oo][lane] = acc[oo];
    }
    __syncthreads();
    if (chalf == 0 && act) {
        float* ob = out + ((b * On + og) * Hn + h) * Wn + wc;
        const float base = (float)(nvalid * Cn);
        #pragma unroll
        for (int oo = 0; oo < OG; ++oo) {
            const int total = acc[oo] + lds[r][oo][lane];
            ob[oo * Hn * Wn] = base - 2.0f * (float)total;  // N - 2*negcount
        }
    }
}

extern "C" void kernel_launch(void* const* d_in, const int* in_sizes, int n_in,
                              void* d_out, int out_size, void* d_ws, size_t ws_size,
                              hipStream_t stream) {
    const float* x  = (const float*)d_in[0];
    const float* wt = (const float*)d_in[1];
    float* o        = (float*)d_out;
    dim3 grid(56, 16);   // 56 row-blocks (4 rows each) x 16 o-groups of 4
    maj3_kernel<<<grid, dim3(512), 0, stream>>>(x, wt, o);
}

// Round 5
// 41.149 us; speedup vs baseline: 8.3843x; 2.2442x over previous
//
#include <hip/hip_runtime.h>

// Maj3: out[b,o,h,w] = sum_{kh,c} sign( sum_{kw} x[b,c,h+kh-1,w+kw-1] * W[o,kw,kh,c] )
// x: (4,64,56,56) f32; W: (64,3,3,64) f32; out: (4,64,56,56) f32.
// Bit-exactness vs numpy required (integer output, threshold 1.36): no FMA
// contraction (contract(off) pragma — verified holding, absmax stable 1.0),
// same mul/add order, sign(0)=0 only from fully-pad rows (skipped).
//
// R5: R4's SGPR_Count=32 revealed weight loads fell off the scalar path —
// chalf derived from threadIdx.x is "divergent" to uniformity analysis, so
// weight fetches became 12 per-lane VMEM loads/c + per-lane addressing.
// Fix: readfirstlane the wave id -> r/chalf/b/h/weight addrs provably uniform
// -> s_load weights, SGPR x-row bases. Also rebalance: 256-thr blocks
// (2 rows x 2 c-halves), grid 112x16 = 1792 blocks = exactly 7 blocks/CU.

#define Cn 64
#define Hn 56
#define Wn 56
#define On 64
#define OG 4    // output channels per block (uniform -> scalar weight loads)
#define CH 32   // channels per wave (c-half)

__global__ __launch_bounds__(256, 7)
void maj3_kernel(const float* __restrict__ x,
                 const float* __restrict__ wt,
                 float* __restrict__ out)
{
#pragma clang fp contract(off)
    __shared__ int lds[2][OG][64];

    const int lane   = threadIdx.x & 63;
    // Wave-uniform by construction; readfirstlane makes it SGPR-provable so
    // everything derived (rows, weight addresses) stays on the scalar path.
    const int wave_u = __builtin_amdgcn_readfirstlane((int)(threadIdx.x >> 6));
    const int r      = wave_u & 1;        // row slot within block (0..1)
    const int chalf  = wave_u >> 1;       // 0 / 1: which 32-channel half
    const int bh     = blockIdx.x * 2 + r;        // 0..223
    const int b      = bh / Hn;
    const int h      = bh - b * Hn;
    const int og     = blockIdx.y * OG;   // block-uniform o base

    const int wc     = lane;              // pixel column; lanes >=56 inactive
    const bool act   = wc < Wn;

    // Clamped tap addresses (never OOB) + per-tap validity for zero padding.
    const int c0 = min(max(wc - 1, 0), Wn - 1);
    const int c1 = min(wc, Wn - 1);
    const int c2 = min(wc + 1, Wn - 1);
    const bool f0 = (wc >= 1);
    const bool f1 = act;
    const bool f2 = (wc + 1 < Wn);

    int acc[OG];
    #pragma unroll
    for (int i = 0; i < OG; ++i) acc[i] = 0;

    int nvalid = 0;
    const float* xb = x + b * (Cn * Hn * Wn) + chalf * (CH * Hn * Wn);

    for (int kh = 0; kh < 3; ++kh) {
        const int row = h + kh - 1;
        if (row < 0 || row >= Hn) continue;   // fully-pad row: sign(0)=0, skip
        ++nvalid;
        const float* xr = xb + row * Wn;
        #pragma unroll 4
        for (int c = 0; c < CH; ++c) {
            const float* xc = xr + c * (Hn * Wn);
            const float v0 = xc[c0];
            const float v1 = xc[c1];
            const float v2 = xc[c2];
            const float x0 = f0 ? v0 : 0.0f;
            const float x1 = f1 ? v1 : 0.0f;
            const float x2 = f2 ? v2 : 0.0f;
            #pragma unroll
            for (int oo = 0; oo < OG; ++oo) {
                // W[o,kw,kh,c] = wt[o*576 + kw*192 + kh*64 + c]; fully uniform
                // address (blockIdx + scalar chalf + loop counters) -> s_load,
                // c-contiguous -> s_load_dwordx4 clusters across the unroll.
                const float* wp = wt + (og + oo) * (3 * 3 * Cn) + kh * Cn
                                + chalf * CH + c;
                const float p0 = x0 * wp[0 * 3 * Cn];   // contract(off):
                const float p1 = x1 * wp[1 * 3 * Cn];   //   plain v_mul_f32,
                const float p2 = x2 * wp[2 * 3 * Cn];   //   no v_fmac fusion
                const float s  = (p0 + p1) + p2;        // same order as reference
                acc[oo] += (int)(__float_as_uint(s) >> 31);  // count negatives
            }
        }
    }

    // Combine the two c-halves' negative-counts (integer -> exact).
    if (chalf == 1) {
        #pragma unroll
        for (int oo = 0; oo < OG; ++oo) lds[r][oo][lane] = acc[oo];
    }
    __syncthreads();
    if (chalf == 0 && act) {
        float* ob = out + ((b * On + og) * Hn + h) * Wn + wc;
        const float base = (float)(nvalid * Cn);
        #pragma unroll
        for (int oo = 0; oo < OG; ++oo) {
            const int total = acc[oo] + lds[r][oo][lane];
            ob[oo * Hn * Wn] = base - 2.0f * (float)total;  // N - 2*negcount
        }
    }
}

extern "C" void kernel_launch(void* const* d_in, const int* in_sizes, int n_in,
                              void* d_out, int out_size, void* d_ws, size_t ws_size,
                              hipStream_t stream) {
    const float* x  = (const float*)d_in[0];
    const float* wt = (const float*)d_in[1];
    float* o        = (float*)d_out;
    dim3 grid(112, 16);   // 112 row-pair blocks x 16 o-groups of 4
    maj3_kernel<<<grid, dim3(256), 0, stream>>>(x, wt, o);
}